// Round 15
// baseline (278.916 us; speedup 1.0000x reference)
//
#include <hip/hip_runtime.h>

// VectorQuantizer: z (32,256,32,32) f32, embedding (1024,256) f32.
// N=32768 rows (n = b*1024 + h*32 + w), D=256, K=1024.
// Out (f32, concat): z_q_st [8388608] (B,C,H,W), vq_loss [1], idx [32768].
// z_flat[n][c] = z[b*262144 + c*1024 + (n & 1023)]
//
// v11 = v10 with:
//  - refineK: 8 rows per wave (lane owns 8 codes/half) -> eT traffic
//    1MB/row -> 128KB/row; 2-deep static prefetch. Per-(row,code) chain is
//    still sequential ascending-d __fmaf_rn -> bit-identical to np-f32 sim.
//  - finishK folded into distK epilogue (direct idx/out writes + atomic
//    compaction of flagged rows).
// distK: 2-chain (zh+zl)*eh MFMA, TAU=1e-3 covers the el-limb omission.
// ws: [0] loss f64; [16) rcount; [64) enorm 4KB; [4352) bp (eh pack 512KB);
//     [1052928) eT 1MB; [2494720) idx_buf; [2625792) rlist.

#define TAU 1.0e-3f

typedef __attribute__((ext_vector_type(8))) short short8b;   // 8 bf16
typedef __attribute__((ext_vector_type(4))) float f32x4;

__device__ __forceinline__ unsigned short f2bf_rne(float x) {
  unsigned int u = __float_as_uint(x);
  unsigned int r = u + 0x7fffu + ((u >> 16) & 1u);
  return (unsigned short)(r >> 16);
}
__device__ __forceinline__ float bf2f(unsigned short s) {
  return __uint_as_float(((unsigned int)s) << 16);
}

__device__ __forceinline__ float np_pairwise256_sq(const float* a) {
  float tot = 0.0f;
#pragma unroll
  for (int blk = 0; blk < 2; ++blk) {
    const float* p = a + blk * 128;
    float r[8];
#pragma unroll
    for (int j = 0; j < 8; ++j) r[j] = __fmul_rn(p[j], p[j]);
    for (int i = 8; i < 128; i += 8) {
#pragma unroll
      for (int j = 0; j < 8; ++j) r[j] = __fadd_rn(r[j], __fmul_rn(p[i + j], p[i + j]));
    }
    float res = __fadd_rn(__fadd_rn(__fadd_rn(r[0], r[1]), __fadd_rn(r[2], r[3])),
                          __fadd_rn(__fadd_rn(r[4], r[5]), __fadd_rn(r[6], r[7])));
    tot = (blk == 0) ? res : __fadd_rn(tot, res);
  }
  return tot;
}

__global__ __launch_bounds__(256) void enormK(const float* __restrict__ emb,
                                              float* __restrict__ enorm) {
  const int k = blockIdx.x * 256 + threadIdx.x;
  enorm[k] = np_pairwise256_sq(emb + (size_t)k * 256);
}

// eT[d][k] = emb[k][d], 32x32 LDS-tiled transpose.
__global__ __launch_bounds__(256) void transK(const float* __restrict__ emb,
                                              float* __restrict__ eT) {
  __shared__ float t[32][33];
  const int k0 = blockIdx.x * 32, d0 = blockIdx.y * 32;
  const int lx = threadIdx.x & 31, ly = threadIdx.x >> 5;
#pragma unroll
  for (int r = 0; r < 4; ++r)
    t[ly + r * 8][lx] = emb[(size_t)(k0 + ly + r * 8) * 256 + d0 + lx];
  __syncthreads();
#pragma unroll
  for (int r = 0; r < 4; ++r)
    eT[(size_t)(d0 + ly + r * 8) * 1024 + k0 + lx] = t[lx][ly + r * 8];
}

// Pack the eh limb: slot ushort-index = ((C*8 + kb)*64 + lane)*8.
// Also zeroes loss_sum/rcount (block 0) — init folded in.
__global__ __launch_bounds__(256) void prepBK(const float* __restrict__ emb,
                                              unsigned short* __restrict__ bp,
                                              double* loss_sum, int* rcount) {
  const int C = blockIdx.x;  // 64 code-blocks of 16
  const int t = threadIdx.x;
  if (C == 0 && t == 0) { *loss_sum = 0.0; *rcount = 0; }
  const int n = t & 15, kb = (t >> 4) & 7, half = t >> 7;
  const float* er = emb + (size_t)(C * 16 + n) * 256 + kb * 32;
#pragma unroll
  for (int ss = 0; ss < 2; ++ss) {
    const int s = half * 2 + ss;
    unsigned int w[4];
#pragma unroll
    for (int p = 0; p < 4; ++p) {
      unsigned short v2[2];
#pragma unroll
      for (int q = 0; q < 2; ++q) v2[q] = f2bf_rne(er[s * 8 + p * 2 + q]);
      w[p] = (unsigned int)v2[0] | ((unsigned int)v2[1] << 16);
    }
    size_t idx = ((size_t)(C * 8 + kb) * 64 + (n + 16 * s)) * 8;
    *(uint4*)(bp + idx) = make_uint4(w[0], w[1], w[2], w[3]);
  }
}

// MFMA distance pass + fused epilogue: wave = 16 rows x 1024 codes.
// Writes idx/out directly; appends rows with gap < TAU to rlist.
__global__ __launch_bounds__(256) void distK(const float* __restrict__ z,
                                             const unsigned short* __restrict__ bp,
                                             const float* __restrict__ enorm,
                                             int* __restrict__ idx_buf,
                                             float* __restrict__ out,
                                             int* __restrict__ rlist,
                                             int* __restrict__ rcount) {
  const int tid = threadIdx.x;
  const int wid = tid >> 6, lane = tid & 63;
  const int R = blockIdx.x * 4 + wid;  // 2048 row-blocks of 16
  const int n0w = R * 16;
  const int b = n0w >> 10, hw0 = n0w & 1023;
  const int s = lane >> 4, m = lane & 15;
  const float* zb = z + (size_t)b * 262144 + hw0 + m;

  short8b az[8], al[8];
#pragma unroll
  for (int kb = 0; kb < 8; ++kb) {
    float f[8];
#pragma unroll
    for (int i = 0; i < 8; ++i)
      f[i] = zb[(size_t)(kb * 32 + s * 8 + i) * 1024];
#pragma unroll
    for (int i = 0; i < 8; ++i) {
      unsigned short hi = f2bf_rne(f[i]);
      az[kb][i] = (short)hi;
      al[kb][i] = (short)f2bf_rne(f[i] - bf2f(hi));
    }
  }

  float m1[4], m2[4];
  int k1i[4];
#pragma unroll
  for (int r = 0; r < 4; ++r) { m1[r] = 3.0e38f; m2[r] = 3.0e38f; k1i[r] = 0; }

  short8b be[8], bn[8];
#pragma unroll
  for (int kb = 0; kb < 8; ++kb)
    be[kb] = *(const short8b*)(bp + ((size_t)kb * 64 + lane) * 8);

  for (int nt = 0; nt < 64; ++nt) {
    f32x4 acc = {0.0f, 0.0f, 0.0f, 0.0f};
    float en = enorm[nt * 16 + m];
#pragma unroll
    for (int kb = 0; kb < 8; ++kb)  // zh . eh
      acc = __builtin_amdgcn_mfma_f32_16x16x32_bf16(az[kb], be[kb], acc, 0, 0, 0);
    const int ntn = (nt < 63) ? nt + 1 : 0;
#pragma unroll
    for (int kb = 0; kb < 8; ++kb)  // prefetch eh(nt+1)
      bn[kb] = *(const short8b*)(bp + (((size_t)ntn * 8 + kb) * 64 + lane) * 8);
#pragma unroll
    for (int kb = 0; kb < 8; ++kb)  // zl . eh
      acc = __builtin_amdgcn_mfma_f32_16x16x32_bf16(al[kb], be[kb], acc, 0, 0, 0);
#pragma unroll
    for (int kb = 0; kb < 8; ++kb) be[kb] = bn[kb];
    const int code = nt * 16 + m;
#pragma unroll
    for (int r = 0; r < 4; ++r) {  // D row = s*4 + r, col = m
      float v = en - 2.0f * acc[r];
      if (v < m1[r]) { m2[r] = m1[r]; m1[r] = v; k1i[r] = code; }
      else if (v < m2[r]) { m2[r] = v; }
    }
  }

#pragma unroll
  for (int r = 0; r < 4; ++r) {
    float a1 = m1[r], a2 = m2[r];
    int ai = k1i[r];
#pragma unroll
    for (int mask = 1; mask < 16; mask <<= 1) {
      float b1 = __shfl_xor(a1, mask);
      float b2 = __shfl_xor(a2, mask);
      int bi = __shfl_xor(ai, mask);
      if (b1 < a1 || (b1 == a1 && bi < ai)) { a2 = fminf(a1, b2); a1 = b1; ai = bi; }
      else { a2 = fminf(a2, b1); }
    }
    if (m == 0) {
      int n = n0w + s * 4 + r;
      idx_buf[n] = ai;
      out[(size_t)8388609 + n] = (float)ai;
      if (a2 - a1 < TAU) {
        int p = atomicAdd(rcount, 1);
        rlist[p] = n;
      }
    }
  }
}

// np-f32 bit-exact re-derivation: 8 rows per wave. Lane owns codes
// h*512 + lane*8 + j (j=0..7) per half h -> 64 indep chains per 32B load.
#define FMA8(r, zv, Ba, Bb)                                   \
  {                                                           \
    bch[r][0] = __fmaf_rn(zv, Ba.x, bch[r][0]);               \
    bch[r][1] = __fmaf_rn(zv, Ba.y, bch[r][1]);               \
    bch[r][2] = __fmaf_rn(zv, Ba.z, bch[r][2]);               \
    bch[r][3] = __fmaf_rn(zv, Ba.w, bch[r][3]);               \
    bch[r][4] = __fmaf_rn(zv, Bb.x, bch[r][4]);               \
    bch[r][5] = __fmaf_rn(zv, Bb.y, bch[r][5]);               \
    bch[r][6] = __fmaf_rn(zv, Bb.z, bch[r][6]);               \
    bch[r][7] = __fmaf_rn(zv, Bb.w, bch[r][7]);               \
  }

__global__ __launch_bounds__(256) void refineK(const float* __restrict__ z,
                                               const float* __restrict__ eT,
                                               const float* __restrict__ enorm,
                                               const int* __restrict__ rlist,
                                               const int* __restrict__ rcount,
                                               int* __restrict__ idx_buf,
                                               float* __restrict__ out) {
  __shared__ float zr[4][8][256];  // 32 KB; per-wave slice, no barriers
  const int tid = threadIdx.x;
  const int wid = tid >> 6, lane = tid & 63;
  const int cnt = *rcount;
  float(*zw)[256] = zr[wid];
  for (int base = (blockIdx.x * 4 + wid) * 8; base < cnt; base += gridDim.x * 32) {
#pragma unroll
    for (int r = 0; r < 8; ++r) {
      int ii = base + r;
      int n = rlist[ii < cnt ? ii : base];
      int bb = n >> 10, hw = n & 1023;
#pragma unroll
      for (int s = 0; s < 4; ++s)
        zw[r][lane + s * 64] = z[(size_t)bb * 262144 + (size_t)(lane + s * 64) * 1024 + hw];
    }
    float a32[8];
#pragma unroll
    for (int r = 0; r < 8; ++r) a32[r] = np_pairwise256_sq(zw[r]);

    float best[8];
    int bi[8];
#pragma unroll
    for (int r = 0; r < 8; ++r) { best[r] = 3.0e38f; bi[r] = 1 << 30; }

    for (int h = 0; h < 2; ++h) {  // halves ascending -> first-index safe
      const float* eb = eT + h * 512 + lane * 8;
      float bch[8][8];
#pragma unroll
      for (int r = 0; r < 8; ++r)
#pragma unroll
        for (int j = 0; j < 8; ++j) bch[r][j] = 0.0f;
      float4 B0a = *(const float4*)(eb);
      float4 B0b = *(const float4*)(eb + 4);
      float4 B1a = *(const float4*)(eb + 1024);
      float4 B1b = *(const float4*)(eb + 1028);
#pragma unroll 1
      for (int d = 0; d < 256; d += 2) {
#pragma unroll
        for (int r = 0; r < 8; ++r) { float zv = zw[r][d]; FMA8(r, zv, B0a, B0b); }
        if (d + 2 < 256) {
          B0a = *(const float4*)(eb + (size_t)(d + 2) * 1024);
          B0b = *(const float4*)(eb + (size_t)(d + 2) * 1024 + 4);
        }
#pragma unroll
        for (int r = 0; r < 8; ++r) { float zv = zw[r][d + 1]; FMA8(r, zv, B1a, B1b); }
        if (d + 3 < 256) {
          B1a = *(const float4*)(eb + (size_t)(d + 3) * 1024);
          B1b = *(const float4*)(eb + (size_t)(d + 3) * 1024 + 4);
        }
      }
#pragma unroll
      for (int j = 0; j < 8; ++j) {  // ascending k within lane
        const int k = h * 512 + lane * 8 + j;
        const float c = enorm[k];
#pragma unroll
        for (int r = 0; r < 8; ++r) {
          float tb = __fmul_rn(2.0f, bch[r][j]);
          float d32 = __fadd_rn(__fsub_rn(a32[r], tb), c);
          if (d32 < best[r]) { best[r] = d32; bi[r] = k; }  // strict < keeps first
        }
      }
    }
#pragma unroll
    for (int r = 0; r < 8; ++r) {
      float bv = best[r];
      int bix = bi[r];
#pragma unroll
      for (int mask = 1; mask < 64; mask <<= 1) {
        float ov = __shfl_xor(bv, mask);
        int oi = __shfl_xor(bix, mask);
        if (ov < bv || (ov == bv && oi < bix)) { bv = ov; bix = oi; }
      }
      int ii = base + r;
      if (lane == 0 && ii < cnt) {
        int n = rlist[ii];
        idx_buf[n] = bix;
        out[(size_t)8388609 + n] = (float)bix;
      }
    }
  }
}

// z_q gather + z_q_st write + loss. Block = 64 rows x 64-channel quarter.
__global__ __launch_bounds__(256) void outputK(const float* __restrict__ z,
                                               const float* __restrict__ emb,
                                               const int* __restrict__ idx_buf,
                                               float* __restrict__ out,
                                               double* __restrict__ loss_sum) {
  __shared__ float el[64 * 65];  // [row][65] pad -> conflict-free staging
  __shared__ int sidx[64];
  __shared__ double sloss[4];

  const int tid = threadIdx.x;
  const int rg = blockIdx.x >> 2;
  const int q = blockIdx.x & 3;       // channel quarter
  const int n0 = rg * 64;
  const int b = n0 >> 10;
  const int hw0 = n0 & 1023;

  if (tid < 64) sidx[tid] = idx_buf[n0 + tid];
  __syncthreads();

#pragma unroll
  for (int rep = 0; rep < 16; ++rep) {
    int idx = rep * 256 + tid;
    int r = idx >> 6, i = idx & 63;
    el[r * 65 + i] = emb[(size_t)sidx[r] * 256 + q * 64 + i];
  }
  __syncthreads();

  const int mq = (tid & 15) * 4;      // m base (4 consecutive hw)
  const int cg = tid >> 4;            // 0..15
  const size_t zb = (size_t)b * 262144 + hw0 + mq;
  double acc = 0.0;
#pragma unroll
  for (int it = 0; it < 4; ++it) {
    int cl = it * 16 + cg;            // local channel 0..63
    int c = q * 64 + cl;
    float4 z4 = *(const float4*)(z + zb + (size_t)c * 1024);
    float e0 = el[(mq + 0) * 65 + cl];
    float e1 = el[(mq + 1) * 65 + cl];
    float e2 = el[(mq + 2) * 65 + cl];
    float e3 = el[(mq + 3) * 65 + cl];
    float d0 = e0 - z4.x, d1 = e1 - z4.y, d2 = e2 - z4.z, d3 = e3 - z4.w;
    float4 o = make_float4(z4.x + d0, z4.y + d1, z4.z + d2, z4.w + d3);
    *(float4*)(out + zb + (size_t)c * 1024) = o;
    acc += (double)(d0 * d0) + (double)(d1 * d1) +
           (double)(d2 * d2) + (double)(d3 * d3);
  }
  for (int mask = 1; mask < 64; mask <<= 1) acc += __shfl_xor(acc, mask);
  if ((tid & 63) == 0) sloss[tid >> 6] = acc;
  __syncthreads();
  if (tid == 0)
    atomicAdd(loss_sum, sloss[0] + sloss[1] + sloss[2] + sloss[3]);
}

__global__ void finalK(const double* loss_sum, float* out) {
  double s = *loss_sum;
  out[8388608] = (float)(1.25 * s / 8388608.0);  // (1+beta)*mean, beta=0.25
}

extern "C" void kernel_launch(void* const* d_in, const int* in_sizes, int n_in,
                              void* d_out, int out_size, void* d_ws, size_t ws_size,
                              hipStream_t stream) {
  const float* z = (const float*)d_in[0];
  const float* emb = (const float*)d_in[1];
  float* out = (float*)d_out;
  char* ws = (char*)d_ws;
  double* loss_sum = (double*)ws;
  int* rcount = (int*)(ws + 16);
  float* enorm = (float*)(ws + 64);
  unsigned short* bp = (unsigned short*)(ws + 4352);  // eh pack (512 KB)
  float* eT = (float*)(ws + 1052928);                 // 1 MB
  int* idx_buf = (int*)(ws + 2494720);
  int* rlist = (int*)(ws + 2625792);

  enormK<<<4, 256, 0, stream>>>(emb, enorm);
  transK<<<dim3(32, 8), 256, 0, stream>>>(emb, eT);
  prepBK<<<64, 256, 0, stream>>>(emb, bp, loss_sum, rcount);
  distK<<<512, 256, 0, stream>>>(z, bp, enorm, idx_buf, out, rlist, rcount);
  refineK<<<1024, 256, 0, stream>>>(z, eT, enorm, rlist, rcount, idx_buf, out);
  outputK<<<2048, 256, 0, stream>>>(z, emb, idx_buf, out, loss_sum);
  finalK<<<1, 1, 0, stream>>>(loss_sum, out);
}

// Round 16
// 194.047 us; speedup vs baseline: 1.4374x; 1.4374x over previous
//
#include <hip/hip_runtime.h>

// VectorQuantizer: z (32,256,32,32) f32, embedding (1024,256) f32.
// N=32768 rows (n = b*1024 + h*32 + w), D=256, K=1024.
// Out (f32, concat): z_q_st [8388608] (B,C,H,W), vq_loss [1], idx [32768].
// z_flat[n][c] = z[b*262144 + c*1024 + (n & 1023)]
//
// v12: revert to 3-chain MFMA pass (r9-proven, TAU=4e-4, cnt~430) after the
// 2-chain/TAU=1e-3 trade proved net-negative (refine ballooned to 175us).
// refineK: proven v9 wave-per-row inner loop, but 2048 single-wave blocks
// with ii=blockIdx.x stride — flagged rows spread across all CUs.
// distK keeps the fused epilogue (idx/out writes + atomic rlist compaction).
// ws: [0] loss f64; [16) rcount; [64) enorm 4KB; [4352) bp (1MB, both limbs);
//     [1052928) eT 1MB; [2494720) idx_buf; [2625792) rlist.

#define TAU 4.0e-4f

typedef __attribute__((ext_vector_type(8))) short short8b;   // 8 bf16
typedef __attribute__((ext_vector_type(4))) float f32x4;

__device__ __forceinline__ unsigned short f2bf_rne(float x) {
  unsigned int u = __float_as_uint(x);
  unsigned int r = u + 0x7fffu + ((u >> 16) & 1u);
  return (unsigned short)(r >> 16);
}
__device__ __forceinline__ float bf2f(unsigned short s) {
  return __uint_as_float(((unsigned int)s) << 16);
}

__device__ __forceinline__ float np_pairwise256_sq(const float* a) {
  float tot = 0.0f;
#pragma unroll
  for (int blk = 0; blk < 2; ++blk) {
    const float* p = a + blk * 128;
    float r[8];
#pragma unroll
    for (int j = 0; j < 8; ++j) r[j] = __fmul_rn(p[j], p[j]);
    for (int i = 8; i < 128; i += 8) {
#pragma unroll
      for (int j = 0; j < 8; ++j) r[j] = __fadd_rn(r[j], __fmul_rn(p[i + j], p[i + j]));
    }
    float res = __fadd_rn(__fadd_rn(__fadd_rn(r[0], r[1]), __fadd_rn(r[2], r[3])),
                          __fadd_rn(__fadd_rn(r[4], r[5]), __fadd_rn(r[6], r[7])));
    tot = (blk == 0) ? res : __fadd_rn(tot, res);
  }
  return tot;
}

__global__ __launch_bounds__(256) void enormK(const float* __restrict__ emb,
                                              float* __restrict__ enorm) {
  const int k = blockIdx.x * 256 + threadIdx.x;
  enorm[k] = np_pairwise256_sq(emb + (size_t)k * 256);
}

// eT[d][k] = emb[k][d], 32x32 LDS-tiled transpose.
__global__ __launch_bounds__(256) void transK(const float* __restrict__ emb,
                                              float* __restrict__ eT) {
  __shared__ float t[32][33];
  const int k0 = blockIdx.x * 32, d0 = blockIdx.y * 32;
  const int lx = threadIdx.x & 31, ly = threadIdx.x >> 5;
#pragma unroll
  for (int r = 0; r < 4; ++r)
    t[ly + r * 8][lx] = emb[(size_t)(k0 + ly + r * 8) * 256 + d0 + lx];
  __syncthreads();
#pragma unroll
  for (int r = 0; r < 4; ++r)
    eT[(size_t)(d0 + ly + r * 8) * 1024 + k0 + lx] = t[lx][ly + r * 8];
}

// B_pack BOTH limbs: slot ushort-index = ((C*16 + limb*8 + kb)*64 + lane)*8.
// lane = n + 16*s holds e[C*16+n][kb*32 + s*8 + i], limb 0 = eh, 1 = el.
// Also zeroes loss_sum/rcount (block 0).
__global__ __launch_bounds__(256) void prepBK(const float* __restrict__ emb,
                                              unsigned short* __restrict__ bp,
                                              double* loss_sum, int* rcount) {
  const int C = blockIdx.x;  // 64 code-blocks of 16
  const int t = threadIdx.x;
  if (C == 0 && t == 0) { *loss_sum = 0.0; *rcount = 0; }
  const int n = t & 15, kb = (t >> 4) & 7, limb = t >> 7;
  const float* er = emb + (size_t)(C * 16 + n) * 256 + kb * 32;
#pragma unroll
  for (int s = 0; s < 4; ++s) {
    unsigned int w[4];
#pragma unroll
    for (int p = 0; p < 4; ++p) {
      unsigned short v2[2];
#pragma unroll
      for (int q = 0; q < 2; ++q) {
        float x = er[s * 8 + p * 2 + q];
        unsigned short hi = f2bf_rne(x);
        v2[q] = (limb == 0) ? hi : f2bf_rne(x - bf2f(hi));
      }
      w[p] = (unsigned int)v2[0] | ((unsigned int)v2[1] << 16);
    }
    size_t idx = ((size_t)(C * 16 + limb * 8 + kb) * 64 + (n + 16 * s)) * 8;
    *(uint4*)(bp + idx) = make_uint4(w[0], w[1], w[2], w[3]);
  }
}

// MFMA distance pass (3 chains) + fused epilogue: wave = 16 rows x 1024 codes.
__global__ __launch_bounds__(256) void distK(const float* __restrict__ z,
                                             const unsigned short* __restrict__ bp,
                                             const float* __restrict__ enorm,
                                             int* __restrict__ idx_buf,
                                             float* __restrict__ out,
                                             int* __restrict__ rlist,
                                             int* __restrict__ rcount) {
  const int tid = threadIdx.x;
  const int wid = tid >> 6, lane = tid & 63;
  const int R = blockIdx.x * 4 + wid;  // 2048 row-blocks of 16
  const int n0w = R * 16;
  const int b = n0w >> 10, hw0 = n0w & 1023;
  const int s = lane >> 4, m = lane & 15;
  const float* zb = z + (size_t)b * 262144 + hw0 + m;

  short8b az[8], al[8];
#pragma unroll
  for (int kb = 0; kb < 8; ++kb) {
    float f[8];
#pragma unroll
    for (int i = 0; i < 8; ++i)
      f[i] = zb[(size_t)(kb * 32 + s * 8 + i) * 1024];
#pragma unroll
    for (int i = 0; i < 8; ++i) {
      unsigned short hi = f2bf_rne(f[i]);
      az[kb][i] = (short)hi;
      al[kb][i] = (short)f2bf_rne(f[i] - bf2f(hi));
    }
  }

  float m1[4], m2[4];
  int k1i[4];
#pragma unroll
  for (int r = 0; r < 4; ++r) { m1[r] = 3.0e38f; m2[r] = 3.0e38f; k1i[r] = 0; }

  short8b be[8], bl[8];
#pragma unroll
  for (int kb = 0; kb < 8; ++kb)  // preload eh(0)
    be[kb] = *(const short8b*)(bp + ((size_t)kb * 64 + lane) * 8);

  for (int nt = 0; nt < 64; ++nt) {
    f32x4 acc = {0.0f, 0.0f, 0.0f, 0.0f};
    float en = enorm[nt * 16 + m];
#pragma unroll
    for (int kb = 0; kb < 8; ++kb)  // zh . eh
      acc = __builtin_amdgcn_mfma_f32_16x16x32_bf16(az[kb], be[kb], acc, 0, 0, 0);
#pragma unroll
    for (int kb = 0; kb < 8; ++kb)  // load el(nt)
      bl[kb] = *(const short8b*)(bp + ((size_t)(nt * 16 + 8 + kb) * 64 + lane) * 8);
#pragma unroll
    for (int kb = 0; kb < 8; ++kb)  // zl . eh
      acc = __builtin_amdgcn_mfma_f32_16x16x32_bf16(al[kb], be[kb], acc, 0, 0, 0);
    if (nt < 63) {
#pragma unroll
      for (int kb = 0; kb < 8; ++kb)  // preload eh(nt+1)
        be[kb] = *(const short8b*)(bp + ((size_t)((nt + 1) * 16 + kb) * 64 + lane) * 8);
    }
#pragma unroll
    for (int kb = 0; kb < 8; ++kb)  // zh . el
      acc = __builtin_amdgcn_mfma_f32_16x16x32_bf16(az[kb], bl[kb], acc, 0, 0, 0);
    const int code = nt * 16 + m;
#pragma unroll
    for (int r = 0; r < 4; ++r) {  // D row = s*4 + r, col = m
      float v = en - 2.0f * acc[r];
      if (v < m1[r]) { m2[r] = m1[r]; m1[r] = v; k1i[r] = code; }
      else if (v < m2[r]) { m2[r] = v; }
    }
  }

#pragma unroll
  for (int r = 0; r < 4; ++r) {
    float a1 = m1[r], a2 = m2[r];
    int ai = k1i[r];
#pragma unroll
    for (int mask = 1; mask < 16; mask <<= 1) {
      float b1 = __shfl_xor(a1, mask);
      float b2 = __shfl_xor(a2, mask);
      int bi = __shfl_xor(ai, mask);
      if (b1 < a1 || (b1 == a1 && bi < ai)) { a2 = fminf(a1, b2); a1 = b1; ai = bi; }
      else { a2 = fminf(a2, b1); }
    }
    if (m == 0) {
      int n = n0w + s * 4 + r;
      idx_buf[n] = ai;
      out[(size_t)8388609 + n] = (float)ai;
      if (a2 - a1 < TAU) {
        int p = atomicAdd(rcount, 1);
        rlist[p] = n;
      }
    }
  }
}

// np-f32 bit-exact re-derivation: ONE WAVE PER BLOCK, one row per iteration,
// rows spread across 2048 blocks (ii = blockIdx.x stride gridDim.x).
__global__ __launch_bounds__(64) void refineK(const float* __restrict__ z,
                                              const float* __restrict__ eT,
                                              const float* __restrict__ enorm,
                                              const int* __restrict__ rlist,
                                              const int* __restrict__ rcount,
                                              int* __restrict__ idx_buf,
                                              float* __restrict__ out) {
  __shared__ float zw[256];  // single wave -> no barriers needed
  const int lane = threadIdx.x;
  const int cnt = *rcount;
  for (int ii = blockIdx.x; ii < cnt; ii += gridDim.x) {
    const int n = rlist[ii];
    const int bb = n >> 10, hw = n & 1023;
#pragma unroll
    for (int s = 0; s < 4; ++s)
      zw[lane + s * 64] = z[(size_t)bb * 262144 + (size_t)(lane + s * 64) * 1024 + hw];
    const float a32 = np_pairwise256_sq(zw);

    float bch[16];
#pragma unroll
    for (int j = 0; j < 16; ++j) bch[j] = 0.0f;
    const float* eb = eT + lane * 16;

    float4 B0[4], B1[4], B2[4], B3[4];
#pragma unroll
    for (int q = 0; q < 4; ++q) {
      B0[q] = *(const float4*)(eb + (size_t)0 * 1024 + q * 4);
      B1[q] = *(const float4*)(eb + (size_t)1 * 1024 + q * 4);
      B2[q] = *(const float4*)(eb + (size_t)2 * 1024 + q * 4);
      B3[q] = *(const float4*)(eb + (size_t)3 * 1024 + q * 4);
    }
#pragma unroll 1
    for (int d = 0; d < 256; d += 4) {
      const bool more = (d + 4) < 256;
      {
        float zv = zw[d];
#pragma unroll
        for (int q = 0; q < 4; ++q) {
          bch[q * 4 + 0] = __fmaf_rn(zv, B0[q].x, bch[q * 4 + 0]);
          bch[q * 4 + 1] = __fmaf_rn(zv, B0[q].y, bch[q * 4 + 1]);
          bch[q * 4 + 2] = __fmaf_rn(zv, B0[q].z, bch[q * 4 + 2]);
          bch[q * 4 + 3] = __fmaf_rn(zv, B0[q].w, bch[q * 4 + 3]);
        }
        if (more) {
#pragma unroll
          for (int q = 0; q < 4; ++q)
            B0[q] = *(const float4*)(eb + (size_t)(d + 4) * 1024 + q * 4);
        }
      }
      {
        float zv = zw[d + 1];
#pragma unroll
        for (int q = 0; q < 4; ++q) {
          bch[q * 4 + 0] = __fmaf_rn(zv, B1[q].x, bch[q * 4 + 0]);
          bch[q * 4 + 1] = __fmaf_rn(zv, B1[q].y, bch[q * 4 + 1]);
          bch[q * 4 + 2] = __fmaf_rn(zv, B1[q].z, bch[q * 4 + 2]);
          bch[q * 4 + 3] = __fmaf_rn(zv, B1[q].w, bch[q * 4 + 3]);
        }
        if (more) {
#pragma unroll
          for (int q = 0; q < 4; ++q)
            B1[q] = *(const float4*)(eb + (size_t)(d + 5) * 1024 + q * 4);
        }
      }
      {
        float zv = zw[d + 2];
#pragma unroll
        for (int q = 0; q < 4; ++q) {
          bch[q * 4 + 0] = __fmaf_rn(zv, B2[q].x, bch[q * 4 + 0]);
          bch[q * 4 + 1] = __fmaf_rn(zv, B2[q].y, bch[q * 4 + 1]);
          bch[q * 4 + 2] = __fmaf_rn(zv, B2[q].z, bch[q * 4 + 2]);
          bch[q * 4 + 3] = __fmaf_rn(zv, B2[q].w, bch[q * 4 + 3]);
        }
        if (more) {
#pragma unroll
          for (int q = 0; q < 4; ++q)
            B2[q] = *(const float4*)(eb + (size_t)(d + 6) * 1024 + q * 4);
        }
      }
      {
        float zv = zw[d + 3];
#pragma unroll
        for (int q = 0; q < 4; ++q) {
          bch[q * 4 + 0] = __fmaf_rn(zv, B3[q].x, bch[q * 4 + 0]);
          bch[q * 4 + 1] = __fmaf_rn(zv, B3[q].y, bch[q * 4 + 1]);
          bch[q * 4 + 2] = __fmaf_rn(zv, B3[q].z, bch[q * 4 + 2]);
          bch[q * 4 + 3] = __fmaf_rn(zv, B3[q].w, bch[q * 4 + 3]);
        }
        if (more) {
#pragma unroll
          for (int q = 0; q < 4; ++q)
            B3[q] = *(const float4*)(eb + (size_t)(d + 7) * 1024 + q * 4);
        }
      }
    }

    float best = 3.0e38f;
    int bi = 1 << 30;
#pragma unroll
    for (int j = 0; j < 16; ++j) {
      const int k = lane * 16 + j;  // ascending -> first-index wins
      float tb = __fmul_rn(2.0f, bch[j]);
      float d32 = __fadd_rn(__fsub_rn(a32, tb), enorm[k]);
      if (d32 < best) { best = d32; bi = k; }
    }
#pragma unroll
    for (int mask = 1; mask < 64; mask <<= 1) {
      float ov = __shfl_xor(best, mask);
      int oi = __shfl_xor(bi, mask);
      if (ov < best || (ov == best && oi < bi)) { best = ov; bi = oi; }
    }
    if (lane == 0) {
      idx_buf[n] = bi;
      out[(size_t)8388609 + n] = (float)bi;
    }
  }
}

// z_q gather + z_q_st write + loss. Block = 64 rows x 64-channel quarter.
__global__ __launch_bounds__(256) void outputK(const float* __restrict__ z,
                                               const float* __restrict__ emb,
                                               const int* __restrict__ idx_buf,
                                               float* __restrict__ out,
                                               double* __restrict__ loss_sum) {
  __shared__ float el[64 * 65];  // [row][65] pad -> conflict-free staging
  __shared__ int sidx[64];
  __shared__ double sloss[4];

  const int tid = threadIdx.x;
  const int rg = blockIdx.x >> 2;
  const int q = blockIdx.x & 3;       // channel quarter
  const int n0 = rg * 64;
  const int b = n0 >> 10;
  const int hw0 = n0 & 1023;

  if (tid < 64) sidx[tid] = idx_buf[n0 + tid];
  __syncthreads();

#pragma unroll
  for (int rep = 0; rep < 16; ++rep) {
    int idx = rep * 256 + tid;
    int r = idx >> 6, i = idx & 63;
    el[r * 65 + i] = emb[(size_t)sidx[r] * 256 + q * 64 + i];
  }
  __syncthreads();

  const int mq = (tid & 15) * 4;      // m base (4 consecutive hw)
  const int cg = tid >> 4;            // 0..15
  const size_t zb = (size_t)b * 262144 + hw0 + mq;
  double acc = 0.0;
#pragma unroll
  for (int it = 0; it < 4; ++it) {
    int cl = it * 16 + cg;            // local channel 0..63
    int c = q * 64 + cl;
    float4 z4 = *(const float4*)(z + zb + (size_t)c * 1024);
    float e0 = el[(mq + 0) * 65 + cl];
    float e1 = el[(mq + 1) * 65 + cl];
    float e2 = el[(mq + 2) * 65 + cl];
    float e3 = el[(mq + 3) * 65 + cl];
    float d0 = e0 - z4.x, d1 = e1 - z4.y, d2 = e2 - z4.z, d3 = e3 - z4.w;
    float4 o = make_float4(z4.x + d0, z4.y + d1, z4.z + d2, z4.w + d3);
    *(float4*)(out + zb + (size_t)c * 1024) = o;
    acc += (double)(d0 * d0) + (double)(d1 * d1) +
           (double)(d2 * d2) + (double)(d3 * d3);
  }
  for (int mask = 1; mask < 64; mask <<= 1) acc += __shfl_xor(acc, mask);
  if ((tid & 63) == 0) sloss[tid >> 6] = acc;
  __syncthreads();
  if (tid == 0)
    atomicAdd(loss_sum, sloss[0] + sloss[1] + sloss[2] + sloss[3]);
}

__global__ void finalK(const double* loss_sum, float* out) {
  double s = *loss_sum;
  out[8388608] = (float)(1.25 * s / 8388608.0);  // (1+beta)*mean, beta=0.25
}

extern "C" void kernel_launch(void* const* d_in, const int* in_sizes, int n_in,
                              void* d_out, int out_size, void* d_ws, size_t ws_size,
                              hipStream_t stream) {
  const float* z = (const float*)d_in[0];
  const float* emb = (const float*)d_in[1];
  float* out = (float*)d_out;
  char* ws = (char*)d_ws;
  double* loss_sum = (double*)ws;
  int* rcount = (int*)(ws + 16);
  float* enorm = (float*)(ws + 64);
  unsigned short* bp = (unsigned short*)(ws + 4352);  // 1 MB (both limbs)
  float* eT = (float*)(ws + 1052928);                 // 1 MB
  int* idx_buf = (int*)(ws + 2494720);
  int* rlist = (int*)(ws + 2625792);

  enormK<<<4, 256, 0, stream>>>(emb, enorm);
  transK<<<dim3(32, 8), 256, 0, stream>>>(emb, eT);
  prepBK<<<64, 256, 0, stream>>>(emb, bp, loss_sum, rcount);
  distK<<<512, 256, 0, stream>>>(z, bp, enorm, idx_buf, out, rlist, rcount);
  refineK<<<2048, 64, 0, stream>>>(z, eT, enorm, rlist, rcount, idx_buf, out);
  outputK<<<2048, 256, 0, stream>>>(z, emb, idx_buf, out, loss_sum);
  finalK<<<1, 1, 0, stream>>>(loss_sum, out);
}